// Round 4
// baseline (540.888 us; speedup 1.0000x reference)
//
#include <hip/hip_runtime.h>
#include <math.h>

typedef float v4f __attribute__((ext_vector_type(4)));

#define C    256
#define CH   128            // C_ = C/2
#define HW_  (512*512)      // 262144
#define EPSV 1e-5f
#define S_SPLIT 16
#define CHUNK (HW_/S_SPLIT) // 16384 elements per K1 block
#define TJ   64
#define NTILE (HW_/TJ)      // 4096 tiles
#define NBLK3 512           // 2 blocks/CU x 256 CU
#define NTHR3 512

// ---------------- K1: partial per-channel sums (unchanged, verified) ----------------
// grid (C, S_SPLIT), block 256. partials[c*S_SPLIT + s] = sum of chunk.
__global__ __launch_bounds__(256) void k1_partial(const float* __restrict__ x,
                                                  float* __restrict__ partials) {
    const int c = blockIdx.x, s = blockIdx.y;
    const v4f* p = (const v4f*)(x + (size_t)c * HW_ + (size_t)s * CHUNK);
    float acc = 0.f;
    #pragma unroll 4
    for (int i = threadIdx.x; i < CHUNK/4; i += 256) {
        v4f t = p[i];
        acc += t.x + t.y + t.z + t.w;
    }
    for (int off = 32; off > 0; off >>= 1) acc += __shfl_down(acc, off, 64);
    __shared__ float red[4];
    int lane = threadIdx.x & 63, wv = threadIdx.x >> 6;
    if (lane == 0) red[wv] = acc;
    __syncthreads();
    if (threadIdx.x == 0) {
        float t = red[0] + red[1] + red[2] + red[3];
        partials[c * S_SPLIT + s] = t;
    }
}

// ---------------- K3: replicated small math + grid-strided elementwise pass ----------------
// Kernel boundary after k1 guarantees partials visibility — no atomics needed.
// Each block independently recomputes a/v/beff (weights are L2-resident after
// first touch per XCD), then processes 8 tiles of 64 positions x 256 channels.
__global__ __launch_bounds__(NTHR3, 4) void k3_fused(
    const float* __restrict__ x,
    const float* __restrict__ w1,  const float* __restrict__ b1,   // ch_cv1
    const float* __restrict__ w3,  const float* __restrict__ b3,   // ch_cv3
    const float* __restrict__ lng, const float* __restrict__ lnb,
    const float* __restrict__ sw1, const float* __restrict__ sb1,  // sp_cv1
    const float* __restrict__ sw2, const float* __restrict__ sb2,  // sp_cv2
    const float* __restrict__ partials,
    float* __restrict__ out)
{
    __shared__ float tile[C][TJ];   // 64 KB; rows 0..9 aliased as small-math scratch
    __shared__ float av[C];
    __shared__ float vv[C];
    __shared__ float pd[8][TJ];
    __shared__ float sj[TJ];
    __shared__ float red1[8], red2[8];
    __shared__ float beff_s;

    const int t = threadIdx.x;
    const int b = blockIdx.x;
    const int lane = t & 63, wv = t >> 6;

    // ---- small math, replicated per block (scratch aliased onto tile rows) ----
    float* xs  = &tile[0][0];   // 256 floats (rows 0-3)
    float* yv  = &tile[4][0];   // 128 floats (rows 4-5)
    float* qv  = &tile[6][0];   // 128 floats (rows 6-7)
    float* s2v = &tile[8][0];   // 128 floats (rows 8-9)

    if (t < C) {
        float sum = 0.f;
        #pragma unroll
        for (int si = 0; si < S_SPLIT; si++) sum += partials[t * S_SPLIT + si];
        xs[t] = sum;
    }
    __syncthreads();

    // y = ch_cv1_w @ xsum + HW*b1 ; q = sp_cv2_w @ (xsum/HW) + b2
    if (t < CH) {
        float acc = (float)HW_ * b1[t];
        const float* wr = w1 + t * C;
        #pragma unroll 16
        for (int c = 0; c < C; c++) acc += wr[c] * xs[c];
        yv[t] = acc;

        float q = 0.f;
        const float* wq = sw2 + t * C;
        #pragma unroll 16
        for (int c = 0; c < C; c++) q += wq[c] * xs[c];
        qv[t] = fmaf(q, 1.f / (float)HW_, sb2[t]);
    }
    __syncthreads();

    // z = ch_cv3_w @ y + b3, LayerNorm over 256 + sigmoid -> av[]
    float z = 0.f;
    if (t < C) {
        z = b3[t];
        const float* wr = w3 + t * CH;
        #pragma unroll 16
        for (int i = 0; i < CH; i++) z += wr[i] * yv[i];
    }
    float s1v = z, sqv = z * z;
    for (int off = 32; off > 0; off >>= 1) {
        s1v += __shfl_down(s1v, off, 64);
        sqv += __shfl_down(sqv, off, 64);
    }
    if (lane == 0) { red1[wv] = s1v; red2[wv] = sqv; }
    __syncthreads();
    {
        float ts = 0.f, tq = 0.f;
        #pragma unroll
        for (int w = 0; w < 8; w++) { ts += red1[w]; tq += red2[w]; }
        if (t < C) {
            float mu  = ts / (float)C;
            float var = tq / (float)C - mu * mu;
            float zn  = (z - mu) * rsqrtf(var + EPSV) * lng[t] + lnb[t];
            av[t] = 1.f / (1.f + expf(-zn));
        }
    }

    // softmax over the 128 spatial logits (qv distinct from s2v rows — no hazard)
    if (t < CH) {
        float m = -1e30f;
        for (int i = 0; i < CH; i++) m = fmaxf(m, qv[i]);
        float den = 0.f;
        for (int i = 0; i < CH; i++) den += expf(qv[i] - m);
        s2v[t] = expf(qv[t] - m) / den;
    }
    __syncthreads();

    // v[c] = sum_i s2[i]*sp_cv1_w[i,c] ; beff = s2 . sp_cv1_b
    if (t < C) {
        float acc = 0.f;
        #pragma unroll 16
        for (int i = 0; i < CH; i++) acc += s2v[i] * sw1[i * C + t];
        vv[t] = acc;
    }
    if (wv == 0) {
        float be = 0.f;
        for (int i = lane; i < CH; i += 64) be += s2v[i] * sb1[i];
        for (int off = 32; off > 0; off >>= 1) be += __shfl_down(be, off, 64);
        if (lane == 0) beff_s = be;
    }
    __syncthreads();   // scratch (tile rows 0-9) dead; av/vv/beff_s ready

    // ---- elementwise pass: 8 tiles per block, grid-strided ----
    for (int tileIdx = b; tileIdx < NTILE; tileIdx += NBLK3) {
        const size_t hw0 = (size_t)tileIdx * TJ;

        #pragma unroll
        for (int i = t; i < C * TJ / 4; i += NTHR3) {     // 8 float4 per thread
            int c = i >> 4, j4 = i & 15;
            v4f val = *(const v4f*)(x + (size_t)c * HW_ + hw0 + j4 * 4);
            *(v4f*)&tile[c][j4 * 4] = val;
        }
        __syncthreads();

        {   // dot: wave g handles 32 channels for all 64 positions
            int j = t & 63, g = t >> 6;
            float acc = 0.f;
            #pragma unroll
            for (int cc = 0; cc < 32; cc++) {
                int c = g * 32 + cc;
                acc += vv[c] * tile[c][j];
            }
            pd[g][j] = acc;
        }
        __syncthreads();
        if (t < TJ) {
            float d = beff_s;
            #pragma unroll
            for (int g = 0; g < 8; g++) d += pd[g][t];
            sj[t] = 1.f / (1.f + expf(-d));
        }
        __syncthreads();

        #pragma unroll
        for (int i = t; i < C * TJ / 4; i += NTHR3) {
            int c = i >> 4, j4 = i & 15;
            v4f val = *(const v4f*)&tile[c][j4 * 4];
            float ac = av[c];
            v4f o;
            o.x = (ac + sj[j4 * 4 + 0]) * val.x;
            o.y = (ac + sj[j4 * 4 + 1]) * val.y;
            o.z = (ac + sj[j4 * 4 + 2]) * val.z;
            o.w = (ac + sj[j4 * 4 + 3]) * val.w;
            __builtin_nontemporal_store(o, (v4f*)(out + (size_t)c * HW_ + hw0 + j4 * 4));
        }
        __syncthreads();   // tile & sj reused next iteration
    }
}

extern "C" void kernel_launch(void* const* d_in, const int* in_sizes, int n_in,
                              void* d_out, int out_size, void* d_ws, size_t ws_size,
                              hipStream_t stream) {
    const float* x    = (const float*)d_in[0];
    const float* w1   = (const float*)d_in[1];   // ch_cv1_w (128,256)
    const float* b1   = (const float*)d_in[2];   // ch_cv1_b (128)
    // d_in[3], d_in[4] = ch_cv2_w/b: dead (softmax over size-1 dim == 1)
    const float* w3   = (const float*)d_in[5];   // ch_cv3_w (256,128)
    const float* b3   = (const float*)d_in[6];   // ch_cv3_b (256)
    const float* lng  = (const float*)d_in[7];
    const float* lnb  = (const float*)d_in[8];
    const float* sw1  = (const float*)d_in[9];   // sp_cv1_w (128,256)
    const float* sb1  = (const float*)d_in[10];  // sp_cv1_b (128)
    const float* sw2  = (const float*)d_in[11];  // sp_cv2_w (128,256)
    const float* sb2  = (const float*)d_in[12];  // sp_cv2_b (128)
    float* out = (float*)d_out;
    float* partials = (float*)d_ws;              // 4096 floats

    hipLaunchKernelGGL(k1_partial, dim3(C, S_SPLIT), dim3(256), 0, stream, x, partials);
    hipLaunchKernelGGL(k3_fused, dim3(NBLK3), dim3(NTHR3), 0, stream,
                       x, w1, b1, w3, b3, lng, lnb, sw1, sb1, sw2, sb2,
                       partials, out);
}

// Round 5
// 534.535 us; speedup vs baseline: 1.0119x; 1.0119x over previous
//
#include <hip/hip_runtime.h>
#include <math.h>

typedef float v4f __attribute__((ext_vector_type(4)));

#define C    256
#define CH   128            // C_ = C/2
#define HW_  (512*512)      // 262144
#define EPSV 1e-5f
#define S_SPLIT 16
#define CHUNK (HW_/S_SPLIT) // 16384 elements per K1 block

// ---------------- K1: partial per-channel sums ----------------
// grid (C, S_SPLIT), block 256. partials[c*S_SPLIT + s] = sum of chunk.
__global__ __launch_bounds__(256) void k1_partial(const float* __restrict__ x,
                                                  float* __restrict__ partials) {
    const int c = blockIdx.x, s = blockIdx.y;
    const v4f* p = (const v4f*)(x + (size_t)c * HW_ + (size_t)s * CHUNK);
    float acc = 0.f;
    #pragma unroll 4
    for (int i = threadIdx.x; i < CHUNK/4; i += 256) {
        v4f t = p[i];
        acc += t.x + t.y + t.z + t.w;
    }
    // wave (64-lane) reduce, then cross-wave via LDS
    for (int off = 32; off > 0; off >>= 1) acc += __shfl_down(acc, off, 64);
    __shared__ float red[4];
    int lane = threadIdx.x & 63, wv = threadIdx.x >> 6;
    if (lane == 0) red[wv] = acc;
    __syncthreads();
    if (threadIdx.x == 0) {
        float t = red[0] + red[1] + red[2] + red[3];
        partials[c * S_SPLIT + s] = t;
    }
}

// ---------------- K2: all the small math, single block of 256 ----------------
__global__ __launch_bounds__(256) void k2_small(
    const float* __restrict__ partials,
    const float* __restrict__ w1,  const float* __restrict__ b1,   // ch_cv1
    const float* __restrict__ w3,  const float* __restrict__ b3,   // ch_cv3
    const float* __restrict__ lng, const float* __restrict__ lnb,
    const float* __restrict__ sw1, const float* __restrict__ sb1,  // sp_cv1
    const float* __restrict__ sw2, const float* __restrict__ sb2,  // sp_cv2
    float* __restrict__ a_out, float* __restrict__ v_out, float* __restrict__ beff_out)
{
    __shared__ float xs[C];      // per-channel sums
    __shared__ float yv[CH];
    __shared__ float qv[CH];
    __shared__ float s2[CH];
    __shared__ float rs[4], rq[4];
    const int t = threadIdx.x;

    // A: finish channel-sum reduction
    float sum = 0.f;
    #pragma unroll
    for (int s = 0; s < S_SPLIT; s++) sum += partials[t * S_SPLIT + s];
    xs[t] = sum;
    __syncthreads();

    // B: y = ch_cv1_w @ xsum + HW*b1   (128 outputs)
    if (t < CH) {
        float acc = (float)HW_ * b1[t];
        const float* wr = w1 + t * C;
        #pragma unroll 16
        for (int c = 0; c < C; c++) acc += wr[c] * xs[c];
        yv[t] = acc;
    }
    __syncthreads();

    // C: z = ch_cv3_w @ y + b3   (256 outputs, one per thread)
    float z = b3[t];
    {
        const float* wr = w3 + t * CH;
        #pragma unroll 16
        for (int i = 0; i < CH; i++) z += wr[i] * yv[i];
    }

    // D: LayerNorm over the 256 z values + sigmoid -> a
    float s1v = z, sqv = z * z;
    for (int off = 32; off > 0; off >>= 1) {
        s1v += __shfl_down(s1v, off, 64);
        sqv += __shfl_down(sqv, off, 64);
    }
    int lane = t & 63, wv = t >> 6;
    if (lane == 0) { rs[wv] = s1v; rq[wv] = sqv; }
    __syncthreads();
    float ts = rs[0] + rs[1] + rs[2] + rs[3];
    float tq = rq[0] + rq[1] + rq[2] + rq[3];
    float mu  = ts / (float)C;
    float var = tq / (float)C - mu * mu;
    float zn = (z - mu) * rsqrtf(var + EPSV) * lng[t] + lnb[t];
    a_out[t] = 1.f / (1.f + expf(-zn));

    // E: spatial softmax logits q = sp_cv2_w @ (xsum/HW) + b2
    if (t < CH) {
        float acc = sb2[t];
        const float* wr = sw2 + t * C;
        const float inv = 1.f / (float)HW_;
        #pragma unroll 16
        for (int c = 0; c < C; c++) acc += wr[c] * (xs[c] * inv);
        qv[t] = acc;
    }
    __syncthreads();
    if (t < CH) {
        float m = -1e30f;
        for (int i = 0; i < CH; i++) m = fmaxf(m, qv[i]);
        float den = 0.f;
        for (int i = 0; i < CH; i++) den += expf(qv[i] - m);
        s2[t] = expf(qv[t] - m) / den;
    }
    __syncthreads();

    // F: v[c] = sum_i s2[i] * sp_cv1_w[i,c]   (coalesced over t)
    {
        float vv = 0.f;
        #pragma unroll 16
        for (int i = 0; i < CH; i++) vv += s2[i] * sw1[i * C + t];
        v_out[t] = vv;
    }

    // G: b_eff = s2 . sp_cv1_b
    if (t == 0) {
        float be = 0.f;
        for (int i = 0; i < CH; i++) be += s2[i] * sb1[i];
        *beff_out = be;
    }
}

// ---------------- K3: main elementwise pass with LDS tile ----------------
// Tile: TJ=64 spatial positions x all 256 channels (64 KB LDS). x read once.
#define TJ 64
#define K3_BLOCK 512

__global__ __launch_bounds__(K3_BLOCK) void k3_main(
    const float* __restrict__ x,
    const float* __restrict__ a, const float* __restrict__ v,
    const float* __restrict__ beff,
    float* __restrict__ out)
{
    __shared__ float tile[C][TJ];   // 64 KB
    __shared__ float av[C];
    __shared__ float vv[C];
    __shared__ float pd[8][TJ];
    __shared__ float sj[TJ];

    const int t = threadIdx.x;
    const size_t hw0 = (size_t)blockIdx.x * TJ;

    if (t < C) { av[t] = a[t]; vv[t] = v[t]; }

    // load: 256*64 floats = 4096 float4, 8 per thread
    #pragma unroll
    for (int i = t; i < C*TJ/4; i += K3_BLOCK) {
        int c = i >> 4, j4 = i & 15;
        v4f val = *(const v4f*)(x + (size_t)c * HW_ + hw0 + j4 * 4);
        *(v4f*)&tile[c][j4 * 4] = val;
    }
    __syncthreads();

    // dot: thread -> (j = t&63, wave g = t>>6 handles 32 channels)
    {
        int j = t & 63, g = t >> 6;
        float acc = 0.f;
        #pragma unroll
        for (int cc = 0; cc < 32; cc++) {
            int c = g * 32 + cc;
            acc += vv[c] * tile[c][j];
        }
        pd[g][j] = acc;
    }
    __syncthreads();
    if (t < TJ) {
        float d = *beff;
        #pragma unroll
        for (int g = 0; g < 8; g++) d += pd[g][t];
        sj[t] = 1.f / (1.f + expf(-d));
    }
    __syncthreads();

    // fused scale + store (nontemporal: out never re-read)
    #pragma unroll
    for (int i = t; i < C*TJ/4; i += K3_BLOCK) {
        int c = i >> 4, j4 = i & 15;
        v4f val = *(const v4f*)&tile[c][j4 * 4];
        float ac = av[c];
        v4f o;
        o.x = (ac + sj[j4*4+0]) * val.x;
        o.y = (ac + sj[j4*4+1]) * val.y;
        o.z = (ac + sj[j4*4+2]) * val.z;
        o.w = (ac + sj[j4*4+3]) * val.w;
        __builtin_nontemporal_store(o, (v4f*)(out + (size_t)c * HW_ + hw0 + j4 * 4));
    }
}

extern "C" void kernel_launch(void* const* d_in, const int* in_sizes, int n_in,
                              void* d_out, int out_size, void* d_ws, size_t ws_size,
                              hipStream_t stream) {
    const float* x    = (const float*)d_in[0];
    const float* w1   = (const float*)d_in[1];   // ch_cv1_w (128,256)
    const float* b1   = (const float*)d_in[2];   // ch_cv1_b (128)
    // d_in[3], d_in[4] = ch_cv2_w/b: dead (softmax over size-1 dim == 1)
    const float* w3   = (const float*)d_in[5];   // ch_cv3_w (256,128)
    const float* b3   = (const float*)d_in[6];   // ch_cv3_b (256)
    const float* lng  = (const float*)d_in[7];
    const float* lnb  = (const float*)d_in[8];
    const float* sw1  = (const float*)d_in[9];   // sp_cv1_w (128,256)
    const float* sb1  = (const float*)d_in[10];  // sp_cv1_b (128)
    const float* sw2  = (const float*)d_in[11];  // sp_cv2_w (128,256)
    const float* sb2  = (const float*)d_in[12];  // sp_cv2_b (128)
    float* out = (float*)d_out;

    float* ws       = (float*)d_ws;
    float* partials = ws;                 // 4096
    float* a_vec    = ws + 4096;          // 256
    float* v_vec    = ws + 4096 + 256;    // 256
    float* beff     = ws + 4096 + 512;    // 1

    hipLaunchKernelGGL(k1_partial, dim3(C, S_SPLIT), dim3(256), 0, stream, x, partials);
    hipLaunchKernelGGL(k2_small, dim3(1), dim3(256), 0, stream,
                       partials, w1, b1, w3, b3, lng, lnb, sw1, sb1, sw2, sb2,
                       a_vec, v_vec, beff);
    hipLaunchKernelGGL(k3_main, dim3(HW_ / TJ), dim3(K3_BLOCK), 0, stream,
                       x, a_vec, v_vec, beff, out);
}